// Round 7
// baseline (590.659 us; speedup 1.0000x reference)
//
#include <hip/hip_runtime.h>
#include <hip/hip_bf16.h>
#include <math.h>

// Mamba block. 8 launches: prep(transposes+rmsnorm+zero) | in_proj DMA-MFMA |
// x_proj MFMA w/ conv+silu fused into A-staging (split-K, atomicAdd) |
// dt MFMA | scan part1/2/3 (conv fused via rolling window, 32 chunks) |
// out_proj DMA-MFMA. Dims fixed: B=4, L=2048, dim=1024, d_inner=2048,
// d_state=16, d_conv=4, dt_rank=64. Rows = B*L = 8192.

#define ROWS 8192
#define DIM 1024
#define DINNER 2048
#define DSTATE 16
#define DTRANK 64
#define LSEQ 2048
#define NCHUNK 32
#define LCHUNK 64    // LSEQ/NCHUNK

#define LOG2E 1.4426950408889634f

typedef unsigned short ushort;
typedef __attribute__((ext_vector_type(8))) short short8;
typedef __attribute__((ext_vector_type(4))) float float4v;

__device__ inline ushort f2bf(float f) {
    __hip_bfloat16 h = __float2bfloat16(f);
    return *reinterpret_cast<ushort*>(&h);
}
__device__ inline float bf2f(ushort u) {
    union { unsigned int i; float f; } w; w.i = ((unsigned int)u) << 16; return w.f;
}

// async global->LDS DMA, 16 B/lane. lds dest = wave-uniform base + lane*16.
__device__ inline void dma16(const void* g, void* l) {
    __builtin_amdgcn_global_load_lds(
        (const __attribute__((address_space(1))) unsigned int*)g,
        (__attribute__((address_space(3))) unsigned int*)l, 16, 0, 0);
}

// ---------------- fused prep: 4 transposes + RMSNorm + dbc zero ------------
__global__ __launch_bounds__(256)
void prep_kernel(const float* __restrict__ in_proj, ushort* __restrict__ bt1,
                 const float* __restrict__ out_proj, ushort* __restrict__ bt2,
                 const float* __restrict__ x_proj, ushort* __restrict__ bt3,
                 const float* __restrict__ dt_w, ushort* __restrict__ bt4,
                 const float* __restrict__ x, const float* __restrict__ rms_w,
                 ushort* __restrict__ xn, float* __restrict__ dbc) {
    __shared__ float tld[32][33];
    __shared__ float red[4];
    int bid = blockIdx.x, tid = threadIdx.x;
    if (bid < 6464) {
        const float* in; ushort* outT; int R, C, bx, by;
        if (bid < 4096)      { in = in_proj;  outT = bt1; R = 1024; C = 4096; bx = bid & 127; by = bid >> 7; }
        else if (bid < 6144) { int t = bid - 4096; in = out_proj; outT = bt2; R = 2048; C = 1024; bx = t & 31; by = t >> 5; }
        else if (bid < 6336) { int t = bid - 6144; in = x_proj;  outT = bt3; R = 2048; C = 96;  bx = t % 3;  by = t / 3; }
        else                 { int t = bid - 6336; in = dt_w;    outT = bt4; R = 64;   C = 2048; bx = t & 63; by = t >> 6; }
        int tx = tid & 31, ty = tid >> 5;
#pragma unroll
        for (int k = 0; k < 4; ++k)
            tld[ty + k * 8][tx] = in[(long)(by * 32 + ty + k * 8) * C + bx * 32 + tx];
        __syncthreads();
#pragma unroll
        for (int k = 0; k < 4; ++k)
            outT[(long)(bx * 32 + ty + k * 8) * R + by * 32 + tx] = f2bf(tld[tx][ty + k * 8]);
    } else if (bid < 14656) {
        int row = bid - 6464;
        float4 xv = ((const float4*)(x + (long)row * DIM))[tid];
        float ss = xv.x * xv.x + xv.y * xv.y + xv.z * xv.z + xv.w * xv.w;
        for (int off = 32; off > 0; off >>= 1) ss += __shfl_down(ss, off);
        if ((tid & 63) == 0) red[tid >> 6] = ss;
        __syncthreads();
        float scale = rsqrtf((red[0] + red[1] + red[2] + red[3]) / DIM + 1e-5f);
        float4 wv = ((const float4*)rms_w)[tid];
        ushort4 ov;
        ov.x = f2bf(xv.x * scale * wv.x);
        ov.y = f2bf(xv.y * scale * wv.y);
        ov.z = f2bf(xv.z * scale * wv.z);
        ov.w = f2bf(xv.w * scale * wv.w);
        ((ushort4*)xn)[(long)row * 256 + tid] = ov;
    } else {
        int idx = (bid - 14656) * 256 + tid;
        float4 z = {0.f, 0.f, 0.f, 0.f};
        ((float4*)dbc)[idx] = z;   // 768*256*4 = 786432 floats
    }
}

// ---------------- DMA-staged bf16 MFMA GEMM (m97 structure) ----------------
// EPI: 0 = bf16 store; 2 = acc + aux[row*ldc+col] -> f32 (residual).
template <int EPI>
__global__ __launch_bounds__(256)
void mfma_gemm_dma(const ushort* __restrict__ A, int lda,
                   const ushort* __restrict__ Bt, int ldbt,
                   void* __restrict__ Cv, int ldc, int K,
                   const float* __restrict__ aux) {
    __shared__ __align__(16) ushort As[128][32];
    __shared__ __align__(16) ushort Bs[128][32];
    int tid = threadIdx.x;
    int wave = tid >> 6, lane = tid & 63;
    int wm = wave >> 1, wn = wave & 1;
    int quad = lane >> 4, l16 = lane & 15;
    int row0 = blockIdx.y * 128, col0 = blockIdx.x * 128;

    int r0 = (wave * 2 + 0) * 16 + (lane >> 2);
    int r1 = (wave * 2 + 1) * 16 + (lane >> 2);
    int ks = (lane & 3) * 8;
    const ushort* a0 = A + (long)(row0 + r0) * lda + ks;
    const ushort* a1 = A + (long)(row0 + r1) * lda + ks;
    const ushort* b0 = Bt + (long)(col0 + r0) * ldbt + ks;
    const ushort* b1 = Bt + (long)(col0 + r1) * ldbt + ks;
    ushort* lA0 = &As[(wave * 2 + 0) * 16][0];
    ushort* lA1 = &As[(wave * 2 + 1) * 16][0];
    ushort* lB0 = &Bs[(wave * 2 + 0) * 16][0];
    ushort* lB1 = &Bs[(wave * 2 + 1) * 16][0];

    float4v acc[4][4] = {};

    for (int k0 = 0; k0 < K; k0 += 32) {
        dma16(a0 + k0, lA0);
        dma16(a1 + k0, lA1);
        dma16(b0 + k0, lB0);
        dma16(b1 + k0, lB1);
        __syncthreads();

        short8 afrag[4], bfrag[4];
#pragma unroll
        for (int i = 0; i < 4; ++i)
            afrag[i] = *reinterpret_cast<const short8*>(&As[wm * 64 + i * 16 + l16][quad * 8]);
#pragma unroll
        for (int j = 0; j < 4; ++j)
            bfrag[j] = *reinterpret_cast<const short8*>(&Bs[wn * 64 + j * 16 + l16][quad * 8]);
#pragma unroll
        for (int i = 0; i < 4; ++i)
#pragma unroll
            for (int j = 0; j < 4; ++j)
                acc[i][j] = __builtin_amdgcn_mfma_f32_16x16x32_bf16(
                    afrag[i], bfrag[j], acc[i][j], 0, 0, 0);
        __syncthreads();
    }

#pragma unroll
    for (int i = 0; i < 4; ++i) {
#pragma unroll
        for (int j = 0; j < 4; ++j) {
            int rbase = row0 + wm * 64 + i * 16 + quad * 4;
            int c = col0 + wn * 64 + j * 16 + l16;
#pragma unroll
            for (int r = 0; r < 4; ++r) {
                float v = acc[i][j][r];
                long idx = (long)(rbase + r) * ldc + c;
                if (EPI == 2) ((float*)Cv)[idx] = v + aux[idx];
                else          ((ushort*)Cv)[idx] = f2bf(v);
            }
        }
    }
}

// ------- x_proj GEMM with conv+silu fused into A-staging, split-K ----------
__global__ __launch_bounds__(256)
void xproj_conv_gemm(const ushort* __restrict__ xz,
                     const float* __restrict__ cw, const float* __restrict__ cb,
                     const ushort* __restrict__ bt3,   // [128][2048]
                     float* __restrict__ dbc) {
    __shared__ __align__(16) ushort As[128][32];
    __shared__ __align__(16) ushort Bs[128][32];
    int tid = threadIdx.x;
    int wave = tid >> 6, lane = tid & 63;
    int wm = wave >> 1, wn = wave & 1;
    int quad = lane >> 4, l16 = lane & 15;
    int row0 = blockIdx.y * 128;
    int ks0 = blockIdx.x * 512;
    int srow = tid >> 2, sseg = tid & 3;

    int r0 = (wave * 2 + 0) * 16 + (lane >> 2);
    int r1 = (wave * 2 + 1) * 16 + (lane >> 2);
    int ksl = (lane & 3) * 8;
    const ushort* b0 = bt3 + (long)r0 * 2048 + ks0 + ksl;
    const ushort* b1 = bt3 + (long)r1 * 2048 + ks0 + ksl;
    ushort* lB0 = &Bs[(wave * 2 + 0) * 16][0];
    ushort* lB1 = &Bs[(wave * 2 + 1) * 16][0];

    float4v acc[4][4] = {};

    for (int k0 = 0; k0 < 512; k0 += 32) {
        dma16(b0 + k0, lB0);
        dma16(b1 + k0, lB1);
#pragma unroll
        for (int it = 0; it < 2; ++it) {
            int r = srow + it * 64;
            long row = row0 + r;
            int l = (int)(row & (LSEQ - 1));
            int cch = ks0 + k0 + sseg * 8;
            short8 v[4];
#pragma unroll
            for (int t = 0; t < 4; ++t) {
                if (l - 3 + t >= 0) v[t] = *(const short8*)&xz[(row - 3 + t) * 4096 + cch];
                else { short8 zz = {0,0,0,0,0,0,0,0}; v[t] = zz; }
            }
            ushort o[8];
#pragma unroll
            for (int j = 0; j < 8; ++j) {
                float4 w = ((const float4*)cw)[cch + j];
                float a = cb[cch + j]
                        + bf2f((ushort)v[0][j]) * w.x + bf2f((ushort)v[1][j]) * w.y
                        + bf2f((ushort)v[2][j]) * w.z + bf2f((ushort)v[3][j]) * w.w;
                a = a / (1.f + __expf(-a));
                o[j] = f2bf(a);
            }
            *(short8*)&As[r][sseg * 8] = *(const short8*)o;
        }
        __syncthreads();

        short8 afrag[4], bfrag[4];
#pragma unroll
        for (int i = 0; i < 4; ++i)
            afrag[i] = *reinterpret_cast<const short8*>(&As[wm * 64 + i * 16 + l16][quad * 8]);
#pragma unroll
        for (int j = 0; j < 4; ++j)
            bfrag[j] = *reinterpret_cast<const short8*>(&Bs[wn * 64 + j * 16 + l16][quad * 8]);
#pragma unroll
        for (int i = 0; i < 4; ++i)
#pragma unroll
            for (int j = 0; j < 4; ++j)
                acc[i][j] = __builtin_amdgcn_mfma_f32_16x16x32_bf16(
                    afrag[i], bfrag[j], acc[i][j], 0, 0, 0);
        __syncthreads();
    }
#pragma unroll
    for (int i = 0; i < 4; ++i) {
#pragma unroll
        for (int j = 0; j < 4; ++j) {
            int rbase = row0 + wm * 64 + i * 16 + quad * 4;
            int c = wn * 64 + j * 16 + l16;
            if (c < 96) {
#pragma unroll
                for (int r = 0; r < 4; ++r)
                    atomicAdd(&dbc[(long)(rbase + r) * 96 + c], acc[i][j][r]);
            }
        }
    }
}

// ---------------- VALU-staged MFMA GEMM for dt (A fp32, K=64) ----------------
__global__ __launch_bounds__(256)
void mfma_gemm_dt(const float* __restrict__ A, int lda,
                  const ushort* __restrict__ Bt, int ldbt,
                  ushort* __restrict__ C, int ldc, int K,
                  const float* __restrict__ aux) {
    __shared__ __align__(16) ushort As[128][40];
    __shared__ __align__(16) ushort Bs[128][40];
    int tid = threadIdx.x;
    int wave = tid >> 6, lane = tid & 63;
    int wm = wave >> 1, wn = wave & 1;
    int quad = lane >> 4, l16 = lane & 15;
    int row0 = blockIdx.y * 128, col0 = blockIdx.x * 128;
    int srow = tid >> 2, sseg = tid & 3;

    float4v acc[4][4] = {};

    for (int k0 = 0; k0 < K; k0 += 32) {
#pragma unroll
        for (int it = 0; it < 2; ++it) {
            int r = srow + it * 64;
            const float* ap = A + (long)(row0 + r) * lda + k0 + sseg * 8;
            ushort tmp[8];
#pragma unroll
            for (int j = 0; j < 8; ++j) tmp[j] = f2bf(ap[j]);
            *reinterpret_cast<short8*>(&As[r][sseg * 8]) =
                *reinterpret_cast<const short8*>(tmp);
            const ushort* bp = Bt + (long)(col0 + r) * ldbt + k0 + sseg * 8;
            *reinterpret_cast<short8*>(&Bs[r][sseg * 8]) =
                *reinterpret_cast<const short8*>(bp);
        }
        __syncthreads();
        short8 afrag[4], bfrag[4];
#pragma unroll
        for (int i = 0; i < 4; ++i)
            afrag[i] = *reinterpret_cast<const short8*>(&As[wm * 64 + i * 16 + l16][quad * 8]);
#pragma unroll
        for (int j = 0; j < 4; ++j)
            bfrag[j] = *reinterpret_cast<const short8*>(&Bs[wn * 64 + j * 16 + l16][quad * 8]);
#pragma unroll
        for (int i = 0; i < 4; ++i)
#pragma unroll
            for (int j = 0; j < 4; ++j)
                acc[i][j] = __builtin_amdgcn_mfma_f32_16x16x32_bf16(
                    afrag[i], bfrag[j], acc[i][j], 0, 0, 0);
        __syncthreads();
    }
#pragma unroll
    for (int i = 0; i < 4; ++i) {
#pragma unroll
        for (int j = 0; j < 4; ++j) {
            int rbase = row0 + wm * 64 + i * 16 + quad * 4;
            int c = col0 + wn * 64 + j * 16 + l16;
#pragma unroll
            for (int r = 0; r < 4; ++r) {
                float v = acc[i][j][r] + aux[c];
                v = (v > 20.f) ? v : log1pf(expf(v));
                C[(long)(rbase + r) * ldc + c] = f2bf(v);
            }
        }
    }
}

// ---------------- chunked selective scan, conv fused -----------------------
// thread = (b,c); 32 chunks of 64. A2[s] = A*log2(e); decay = exp2(d*A2).
__global__ __launch_bounds__(256)
void scan_part1(const ushort* __restrict__ xz,     // xi at row*4096 + c
                const ushort* __restrict__ dlt,    // delta [8192][2048]
                const float* __restrict__ dbc,     // [ROWS][96]: dt|B|C
                const float* __restrict__ A_log,
                const float* __restrict__ cw, const float* __restrict__ cb,
                float* __restrict__ hbuf,          // [B][G][16][2048]
                float* __restrict__ sdbuf) {       // [B][G][2048]
    int c = blockIdx.y * 256 + threadIdx.x;
    int b = blockIdx.z, g = blockIdx.x;
    float A2[16];
#pragma unroll
    for (int s = 0; s < 16; ++s) A2[s] = -__expf(A_log[c * 16 + s]) * LOG2E;
    float4 w = ((const float4*)cw)[c];
    float cbc = cb[c];
    float h[16] = {};
    float sumd = 0.f;
    long row0 = (long)b * LSEQ + (long)g * LCHUNK;
    int l0 = g * LCHUNK;
    float x0 = (l0 >= 3) ? bf2f(xz[(row0 - 3) * 4096 + c]) : 0.f;
    float x1 = (l0 >= 2) ? bf2f(xz[(row0 - 2) * 4096 + c]) : 0.f;
    float x2 = (l0 >= 1) ? bf2f(xz[(row0 - 1) * 4096 + c]) : 0.f;
    long row = row0;
#pragma unroll 2
    for (int l = 0; l < LCHUNK; ++l, ++row) {
        float x3 = bf2f(xz[row * 4096 + c]);
        float xc = cbc + x0 * w.x + x1 * w.y + x2 * w.z + x3 * w.w;
        xc = xc / (1.f + __expf(-xc));
        x0 = x1; x1 = x2; x2 = x3;
        float d = bf2f(dlt[row * 2048 + c]);
        const float* __restrict__ bc = dbc + row * 96;
        sumd += d;
        float dx = d * xc;
#pragma unroll
        for (int s = 0; s < 16; ++s)
            h[s] = exp2f(d * A2[s]) * h[s] + dx * bc[64 + s];
    }
    long hb = ((long)(b * NCHUNK + g) * 16) * 2048 + c;
#pragma unroll
    for (int s = 0; s < 16; ++s) hbuf[hb + (long)s * 2048] = h[s];
    sdbuf[(long)(b * NCHUNK + g) * 2048 + c] = sumd;
}

// part2: serial combine over chunks; hbuf becomes h_in per chunk.
__global__ __launch_bounds__(256)
void scan_part2(float* __restrict__ hbuf, const float* __restrict__ sdbuf,
                const float* __restrict__ A_log) {
    int gl = blockIdx.x * 256 + threadIdx.x;   // 131072 threads
    int c = gl & 2047, s = (gl >> 11) & 15, b = gl >> 15;
    float A2 = -__expf(A_log[c * 16 + s]) * LOG2E;
    float hrun = 0.f;
    for (int g = 0; g < NCHUNK; ++g) {
        long hi = ((long)(b * NCHUNK + g) * 16 + s) * 2048 + c;
        float hout = hbuf[hi];
        float sd = sdbuf[(long)(b * NCHUNK + g) * 2048 + c];
        hbuf[hi] = hrun;
        hrun = exp2f(A2 * sd) * hrun + hout;
    }
}

// part3: re-scan from h_in; y = sum_s h*C; D-skip + SiLU gate; y -> dlt (bf16).
__global__ __launch_bounds__(256)
void scan_part3(const ushort* __restrict__ xz,    // xi + z halves (read-only)
                ushort* __restrict__ dlt,         // delta in / gated y out
                const float* __restrict__ dbc,
                const float* __restrict__ A_log,
                const float* __restrict__ cw, const float* __restrict__ cb,
                const float* __restrict__ Dp,
                const float* __restrict__ hbuf) {
    int c = blockIdx.y * 256 + threadIdx.x;
    int b = blockIdx.z, g = blockIdx.x;
    float A2[16], h[16];
#pragma unroll
    for (int s = 0; s < 16; ++s) A2[s] = -__expf(A_log[c * 16 + s]) * LOG2E;
    long hb = ((long)(b * NCHUNK + g) * 16) * 2048 + c;
#pragma unroll
    for (int s = 0; s < 16; ++s) h[s] = hbuf[hb + (long)s * 2048];
    float4 w = ((const float4*)cw)[c];
    float cbc = cb[c];
    float Dc = Dp[c];
    long row0 = (long)b * LSEQ + (long)g * LCHUNK;
    int l0 = g * LCHUNK;
    float x0 = (l0 >= 3) ? bf2f(xz[(row0 - 3) * 4096 + c]) : 0.f;
    float x1 = (l0 >= 2) ? bf2f(xz[(row0 - 2) * 4096 + c]) : 0.f;
    float x2 = (l0 >= 1) ? bf2f(xz[(row0 - 1) * 4096 + c]) : 0.f;
    long row = row0;
#pragma unroll 2
    for (int l = 0; l < LCHUNK; ++l, ++row) {
        float x3 = bf2f(xz[row * 4096 + c]);
        float xc = cbc + x0 * w.x + x1 * w.y + x2 * w.z + x3 * w.w;
        xc = xc / (1.f + __expf(-xc));
        x0 = x1; x1 = x2; x2 = x3;
        float d = bf2f(dlt[row * 2048 + c]);
        float z = bf2f(xz[row * 4096 + 2048 + c]);
        const float* __restrict__ bc = dbc + row * 96;
        float dx = d * xc;
        float y = 0.f;
#pragma unroll
        for (int s = 0; s < 16; ++s) {
            h[s] = exp2f(d * A2[s]) * h[s] + dx * bc[64 + s];
            y += h[s] * bc[80 + s];
        }
        float yv = (y + xc * Dc) * (z / (1.f + __expf(-z)));
        dlt[row * 2048 + c] = f2bf(yv);
    }
}

extern "C" void kernel_launch(void* const* d_in, const int* in_sizes, int n_in,
                              void* d_out, int out_size, void* d_ws, size_t ws_size,
                              hipStream_t stream) {
    const float* x        = (const float*)d_in[0];
    const float* rms_w    = (const float*)d_in[1];
    const float* in_proj  = (const float*)d_in[2];
    const float* conv_w   = (const float*)d_in[3];
    const float* conv_b   = (const float*)d_in[4];
    const float* x_proj   = (const float*)d_in[5];
    const float* dt_w     = (const float*)d_in[6];
    const float* dt_b     = (const float*)d_in[7];
    const float* A_log    = (const float*)d_in[8];
    const float* Dp       = (const float*)d_in[9];
    const float* out_proj = (const float*)d_in[10];
    float* out = (float*)d_out;

    char* p = (char*)d_ws;
    ushort* xz  = (ushort*)p;   p += (size_t)ROWS * 4096 * 2;   // 64 MB  xi|z
    ushort* dlt = (ushort*)p;   p += (size_t)ROWS * 2048 * 2;   // 32 MB  delta -> gated y
    float*  dbc = (float*)p;    p += (size_t)ROWS * 96 * 4;     // 3 MB
    ushort* bt1 = (ushort*)p;   p += (size_t)4096 * 1024 * 2;   // 8 MB   in_proj^T
    ushort* bt2 = (ushort*)p;   p += (size_t)1024 * 2048 * 2;   // 4 MB   out_proj^T
    ushort* bt3 = (ushort*)p;   p += (size_t)128 * 2048 * 2;    // 512 KB x_proj^T (96 rows valid)
    ushort* bt4 = (ushort*)p;   p += (size_t)2048 * 64 * 2;     // 256 KB dt_w^T
    ushort* xn  = (ushort*)p;   p += (size_t)ROWS * 1024 * 2;   // 16.78 MB (dead after in_proj)
    float* sdbuf = (float*)p;   p += (size_t)4 * NCHUNK * 2048 * 4; // 1 MB
    float* hbuf  = (float*)xn;  // 4*32*16*2048*4 = 16.78 MB, overlays xn exactly
    // total ~129 MiB

    // 1. prep: weight transposes + RMSNorm -> xn bf16 + dbc zero
    prep_kernel<<<15424, 256, 0, stream>>>(in_proj, bt1, out_proj, bt2,
                                           x_proj, bt3, dt_w, bt4,
                                           x, rms_w, xn, dbc);
    // 2. xz = xn @ in_proj  [8192,1024]@[1024,4096] -> bf16 (DMA MFMA)
    mfma_gemm_dma<0><<<dim3(4096 / 128, ROWS / 128), 256, 0, stream>>>(
        xn, DIM, bt1, 1024, xz, 4096, DIM, nullptr);
    // 3. dbc += silu(conv(xi)) @ x_proj  (fused conv, split-K x4, atomics)
    xproj_conv_gemm<<<dim3(4, ROWS / 128), 256, 0, stream>>>(
        xz, conv_w, conv_b, bt3, dbc);
    // 4. dlt = softplus(dbc[:,:64] @ dt_w + dt_b) -> bf16
    mfma_gemm_dt<<<dim3(2048 / 128, ROWS / 128), 256, 0, stream>>>(
        dbc, 96, bt4, 64, dlt, 2048, DTRANK, dt_b);
    // 5-7. chunked selective scan (conv recomputed via rolling window)
    scan_part1<<<dim3(NCHUNK, DINNER / 256, 4), 256, 0, stream>>>(
        xz, dlt, dbc, A_log, conv_w, conv_b, hbuf, sdbuf);
    scan_part2<<<512, 256, 0, stream>>>(hbuf, sdbuf, A_log);
    scan_part3<<<dim3(NCHUNK, DINNER / 256, 4), 256, 0, stream>>>(
        xz, dlt, dbc, A_log, conv_w, conv_b, Dp, hbuf);
    // 8. out = x + y @ out_proj  [8192,2048]@[2048,1024] -> f32 (DMA MFMA)
    mfma_gemm_dma<2><<<dim3(DIM / 128, ROWS / 128), 256, 0, stream>>>(
        dlt, 2048, bt2, DINNER, out, DIM, DINNER, x);
}

// Round 8
// 489.073 us; speedup vs baseline: 1.2077x; 1.2077x over previous
//
#include <hip/hip_runtime.h>
#include <hip/hip_bf16.h>
#include <math.h>

// Mamba block. 8 launches: prep(transposes+rmsnorm+zero) | in_proj DMA-MFMA |
// x_proj MFMA w/ conv+silu fused into A-staging (split-K, atomicAdd) |
// dt MFMA | scan part1/2/3 (conv fused via rolling window, 32 chunks) |
// out_proj DMA-MFMA. Dims fixed: B=4, L=2048, dim=1024, d_inner=2048,
// d_state=16, d_conv=4, dt_rank=64. Rows = B*L = 8192.

#define ROWS 8192
#define DIM 1024
#define DINNER 2048
#define DSTATE 16
#define DTRANK 64
#define LSEQ 2048
#define NCHUNK 32
#define LCHUNK 64    // LSEQ/NCHUNK

#define LOG2E 1.4426950408889634f

typedef unsigned short ushort;
typedef __attribute__((ext_vector_type(8))) short short8;
typedef __attribute__((ext_vector_type(4))) float float4v;

__device__ inline ushort f2bf(float f) {
    __hip_bfloat16 h = __float2bfloat16(f);
    return *reinterpret_cast<ushort*>(&h);
}
__device__ inline float bf2f(ushort u) {
    union { unsigned int i; float f; } w; w.i = ((unsigned int)u) << 16; return w.f;
}

// raw v_exp_f32 (2^x), single instruction. NOT libm exp2f (precise, ~6 instr).
__device__ inline float fexp2(float x) {
#if __has_builtin(__builtin_amdgcn_exp2f)
    return __builtin_amdgcn_exp2f(x);
#else
    return __expf(x * 0.69314718056f);
#endif
}

// async global->LDS DMA, 16 B/lane. lds dest = wave-uniform base + lane*16.
__device__ inline void dma16(const void* g, void* l) {
    __builtin_amdgcn_global_load_lds(
        (const __attribute__((address_space(1))) unsigned int*)g,
        (__attribute__((address_space(3))) unsigned int*)l, 16, 0, 0);
}

// ---------------- fused prep: 4 transposes + RMSNorm + dbc zero ------------
__global__ __launch_bounds__(256)
void prep_kernel(const float* __restrict__ in_proj, ushort* __restrict__ bt1,
                 const float* __restrict__ out_proj, ushort* __restrict__ bt2,
                 const float* __restrict__ x_proj, ushort* __restrict__ bt3,
                 const float* __restrict__ dt_w, ushort* __restrict__ bt4,
                 const float* __restrict__ x, const float* __restrict__ rms_w,
                 ushort* __restrict__ xn, float* __restrict__ dbc) {
    __shared__ float tld[32][33];
    __shared__ float red[4];
    int bid = blockIdx.x, tid = threadIdx.x;
    if (bid < 6464) {
        const float* in; ushort* outT; int R, C, bx, by;
        if (bid < 4096)      { in = in_proj;  outT = bt1; R = 1024; C = 4096; bx = bid & 127; by = bid >> 7; }
        else if (bid < 6144) { int t = bid - 4096; in = out_proj; outT = bt2; R = 2048; C = 1024; bx = t & 31; by = t >> 5; }
        else if (bid < 6336) { int t = bid - 6144; in = x_proj;  outT = bt3; R = 2048; C = 96;  bx = t % 3;  by = t / 3; }
        else                 { int t = bid - 6336; in = dt_w;    outT = bt4; R = 64;   C = 2048; bx = t & 63; by = t >> 6; }
        int tx = tid & 31, ty = tid >> 5;
#pragma unroll
        for (int k = 0; k < 4; ++k)
            tld[ty + k * 8][tx] = in[(long)(by * 32 + ty + k * 8) * C + bx * 32 + tx];
        __syncthreads();
#pragma unroll
        for (int k = 0; k < 4; ++k)
            outT[(long)(bx * 32 + ty + k * 8) * R + by * 32 + tx] = f2bf(tld[tx][ty + k * 8]);
    } else if (bid < 14656) {
        int row = bid - 6464;
        float4 xv = ((const float4*)(x + (long)row * DIM))[tid];
        float ss = xv.x * xv.x + xv.y * xv.y + xv.z * xv.z + xv.w * xv.w;
        for (int off = 32; off > 0; off >>= 1) ss += __shfl_down(ss, off);
        if ((tid & 63) == 0) red[tid >> 6] = ss;
        __syncthreads();
        float scale = rsqrtf((red[0] + red[1] + red[2] + red[3]) / DIM + 1e-5f);
        float4 wv = ((const float4*)rms_w)[tid];
        ushort4 ov;
        ov.x = f2bf(xv.x * scale * wv.x);
        ov.y = f2bf(xv.y * scale * wv.y);
        ov.z = f2bf(xv.z * scale * wv.z);
        ov.w = f2bf(xv.w * scale * wv.w);
        ((ushort4*)xn)[(long)row * 256 + tid] = ov;
    } else {
        int idx = (bid - 14656) * 256 + tid;
        float4 z = {0.f, 0.f, 0.f, 0.f};
        ((float4*)dbc)[idx] = z;   // 768*256*4 = 786432 floats
    }
}

// ---------------- DMA-staged bf16 MFMA GEMM (m97 structure) ----------------
// EPI: 0 = bf16 store; 2 = acc + aux[row*ldc+col] -> f32 (residual).
template <int EPI>
__global__ __launch_bounds__(256)
void mfma_gemm_dma(const ushort* __restrict__ A, int lda,
                   const ushort* __restrict__ Bt, int ldbt,
                   void* __restrict__ Cv, int ldc, int K,
                   const float* __restrict__ aux) {
    __shared__ __align__(16) ushort As[128][32];
    __shared__ __align__(16) ushort Bs[128][32];
    int tid = threadIdx.x;
    int wave = tid >> 6, lane = tid & 63;
    int wm = wave >> 1, wn = wave & 1;
    int quad = lane >> 4, l16 = lane & 15;
    int row0 = blockIdx.y * 128, col0 = blockIdx.x * 128;

    int r0 = (wave * 2 + 0) * 16 + (lane >> 2);
    int r1 = (wave * 2 + 1) * 16 + (lane >> 2);
    int ks = (lane & 3) * 8;
    const ushort* a0 = A + (long)(row0 + r0) * lda + ks;
    const ushort* a1 = A + (long)(row0 + r1) * lda + ks;
    const ushort* b0 = Bt + (long)(col0 + r0) * ldbt + ks;
    const ushort* b1 = Bt + (long)(col0 + r1) * ldbt + ks;
    ushort* lA0 = &As[(wave * 2 + 0) * 16][0];
    ushort* lA1 = &As[(wave * 2 + 1) * 16][0];
    ushort* lB0 = &Bs[(wave * 2 + 0) * 16][0];
    ushort* lB1 = &Bs[(wave * 2 + 1) * 16][0];

    float4v acc[4][4] = {};

    for (int k0 = 0; k0 < K; k0 += 32) {
        dma16(a0 + k0, lA0);
        dma16(a1 + k0, lA1);
        dma16(b0 + k0, lB0);
        dma16(b1 + k0, lB1);
        __syncthreads();

        short8 afrag[4], bfrag[4];
#pragma unroll
        for (int i = 0; i < 4; ++i)
            afrag[i] = *reinterpret_cast<const short8*>(&As[wm * 64 + i * 16 + l16][quad * 8]);
#pragma unroll
        for (int j = 0; j < 4; ++j)
            bfrag[j] = *reinterpret_cast<const short8*>(&Bs[wn * 64 + j * 16 + l16][quad * 8]);
#pragma unroll
        for (int i = 0; i < 4; ++i)
#pragma unroll
            for (int j = 0; j < 4; ++j)
                acc[i][j] = __builtin_amdgcn_mfma_f32_16x16x32_bf16(
                    afrag[i], bfrag[j], acc[i][j], 0, 0, 0);
        __syncthreads();
    }

#pragma unroll
    for (int i = 0; i < 4; ++i) {
#pragma unroll
        for (int j = 0; j < 4; ++j) {
            int rbase = row0 + wm * 64 + i * 16 + quad * 4;
            int c = col0 + wn * 64 + j * 16 + l16;
#pragma unroll
            for (int r = 0; r < 4; ++r) {
                float v = acc[i][j][r];
                long idx = (long)(rbase + r) * ldc + c;
                if (EPI == 2) ((float*)Cv)[idx] = v + aux[idx];
                else          ((ushort*)Cv)[idx] = f2bf(v);
            }
        }
    }
}

// ------- x_proj GEMM with conv+silu fused into A-staging, split-K ----------
__global__ __launch_bounds__(256)
void xproj_conv_gemm(const ushort* __restrict__ xz,
                     const float* __restrict__ cw, const float* __restrict__ cb,
                     const ushort* __restrict__ bt3,   // [128][2048]
                     float* __restrict__ dbc) {
    __shared__ __align__(16) ushort As[128][32];
    __shared__ __align__(16) ushort Bs[128][32];
    int tid = threadIdx.x;
    int wave = tid >> 6, lane = tid & 63;
    int wm = wave >> 1, wn = wave & 1;
    int quad = lane >> 4, l16 = lane & 15;
    int row0 = blockIdx.y * 128;
    int ks0 = blockIdx.x * 512;
    int srow = tid >> 2, sseg = tid & 3;

    int r0 = (wave * 2 + 0) * 16 + (lane >> 2);
    int r1 = (wave * 2 + 1) * 16 + (lane >> 2);
    int ksl = (lane & 3) * 8;
    const ushort* b0 = bt3 + (long)r0 * 2048 + ks0 + ksl;
    const ushort* b1 = bt3 + (long)r1 * 2048 + ks0 + ksl;
    ushort* lB0 = &Bs[(wave * 2 + 0) * 16][0];
    ushort* lB1 = &Bs[(wave * 2 + 1) * 16][0];

    float4v acc[4][4] = {};

    for (int k0 = 0; k0 < 512; k0 += 32) {
        dma16(b0 + k0, lB0);
        dma16(b1 + k0, lB1);
#pragma unroll
        for (int it = 0; it < 2; ++it) {
            int r = srow + it * 64;
            long row = row0 + r;
            int l = (int)(row & (LSEQ - 1));
            int cch = ks0 + k0 + sseg * 8;
            short8 v[4];
#pragma unroll
            for (int t = 0; t < 4; ++t) {
                if (l - 3 + t >= 0) v[t] = *(const short8*)&xz[(row - 3 + t) * 4096 + cch];
                else { short8 zz = {0,0,0,0,0,0,0,0}; v[t] = zz; }
            }
            ushort o[8];
#pragma unroll
            for (int j = 0; j < 8; ++j) {
                float4 w = ((const float4*)cw)[cch + j];
                float a = cb[cch + j]
                        + bf2f((ushort)v[0][j]) * w.x + bf2f((ushort)v[1][j]) * w.y
                        + bf2f((ushort)v[2][j]) * w.z + bf2f((ushort)v[3][j]) * w.w;
                a = a / (1.f + __expf(-a));
                o[j] = f2bf(a);
            }
            *(short8*)&As[r][sseg * 8] = *(const short8*)o;
        }
        __syncthreads();

        short8 afrag[4], bfrag[4];
#pragma unroll
        for (int i = 0; i < 4; ++i)
            afrag[i] = *reinterpret_cast<const short8*>(&As[wm * 64 + i * 16 + l16][quad * 8]);
#pragma unroll
        for (int j = 0; j < 4; ++j)
            bfrag[j] = *reinterpret_cast<const short8*>(&Bs[wn * 64 + j * 16 + l16][quad * 8]);
#pragma unroll
        for (int i = 0; i < 4; ++i)
#pragma unroll
            for (int j = 0; j < 4; ++j)
                acc[i][j] = __builtin_amdgcn_mfma_f32_16x16x32_bf16(
                    afrag[i], bfrag[j], acc[i][j], 0, 0, 0);
        __syncthreads();
    }
#pragma unroll
    for (int i = 0; i < 4; ++i) {
#pragma unroll
        for (int j = 0; j < 4; ++j) {
            int rbase = row0 + wm * 64 + i * 16 + quad * 4;
            int c = wn * 64 + j * 16 + l16;
            if (c < 96) {
#pragma unroll
                for (int r = 0; r < 4; ++r)
                    atomicAdd(&dbc[(long)(rbase + r) * 96 + c], acc[i][j][r]);
            }
        }
    }
}

// ---------------- VALU-staged MFMA GEMM for dt (A fp32, K=64) ----------------
__global__ __launch_bounds__(256)
void mfma_gemm_dt(const float* __restrict__ A, int lda,
                  const ushort* __restrict__ Bt, int ldbt,
                  ushort* __restrict__ C, int ldc, int K,
                  const float* __restrict__ aux) {
    __shared__ __align__(16) ushort As[128][40];
    __shared__ __align__(16) ushort Bs[128][40];
    int tid = threadIdx.x;
    int wave = tid >> 6, lane = tid & 63;
    int wm = wave >> 1, wn = wave & 1;
    int quad = lane >> 4, l16 = lane & 15;
    int row0 = blockIdx.y * 128, col0 = blockIdx.x * 128;
    int srow = tid >> 2, sseg = tid & 3;

    float4v acc[4][4] = {};

    for (int k0 = 0; k0 < K; k0 += 32) {
#pragma unroll
        for (int it = 0; it < 2; ++it) {
            int r = srow + it * 64;
            const float* ap = A + (long)(row0 + r) * lda + k0 + sseg * 8;
            ushort tmp[8];
#pragma unroll
            for (int j = 0; j < 8; ++j) tmp[j] = f2bf(ap[j]);
            *reinterpret_cast<short8*>(&As[r][sseg * 8]) =
                *reinterpret_cast<const short8*>(tmp);
            const ushort* bp = Bt + (long)(col0 + r) * ldbt + k0 + sseg * 8;
            *reinterpret_cast<short8*>(&Bs[r][sseg * 8]) =
                *reinterpret_cast<const short8*>(bp);
        }
        __syncthreads();
        short8 afrag[4], bfrag[4];
#pragma unroll
        for (int i = 0; i < 4; ++i)
            afrag[i] = *reinterpret_cast<const short8*>(&As[wm * 64 + i * 16 + l16][quad * 8]);
#pragma unroll
        for (int j = 0; j < 4; ++j)
            bfrag[j] = *reinterpret_cast<const short8*>(&Bs[wn * 64 + j * 16 + l16][quad * 8]);
#pragma unroll
        for (int i = 0; i < 4; ++i)
#pragma unroll
            for (int j = 0; j < 4; ++j)
                acc[i][j] = __builtin_amdgcn_mfma_f32_16x16x32_bf16(
                    afrag[i], bfrag[j], acc[i][j], 0, 0, 0);
        __syncthreads();
    }
#pragma unroll
    for (int i = 0; i < 4; ++i) {
#pragma unroll
        for (int j = 0; j < 4; ++j) {
            int rbase = row0 + wm * 64 + i * 16 + quad * 4;
            int c = col0 + wn * 64 + j * 16 + l16;
#pragma unroll
            for (int r = 0; r < 4; ++r) {
                float v = acc[i][j][r] + aux[c];
                v = (v > 20.f) ? v : __logf(1.f + __expf(v));
                C[(long)(rbase + r) * ldc + c] = f2bf(v);
            }
        }
    }
}

// ---------------- chunked selective scan, conv fused -----------------------
// thread = (b,c); 32 chunks of 64. A2[s] = A*log2(e); decay = v_exp(d*A2).
__global__ __launch_bounds__(256)
void scan_part1(const ushort* __restrict__ xz,     // xi at row*4096 + c
                const ushort* __restrict__ dlt,    // delta [8192][2048]
                const float* __restrict__ dbc,     // [ROWS][96]: dt|B|C
                const float* __restrict__ A_log,
                const float* __restrict__ cw, const float* __restrict__ cb,
                float* __restrict__ hbuf,          // [B][G][16][2048]
                float* __restrict__ sdbuf) {       // [B][G][2048]
    int c = blockIdx.y * 256 + threadIdx.x;
    int b = blockIdx.z, g = blockIdx.x;
    float A2[16];
#pragma unroll
    for (int s = 0; s < 16; ++s) A2[s] = -__expf(A_log[c * 16 + s]) * LOG2E;
    float4 w = ((const float4*)cw)[c];
    float cbc = cb[c];
    float h[16] = {};
    float sumd = 0.f;
    long row0 = (long)b * LSEQ + (long)g * LCHUNK;
    int l0 = g * LCHUNK;
    float x0 = (l0 >= 3) ? bf2f(xz[(row0 - 3) * 4096 + c]) : 0.f;
    float x1 = (l0 >= 2) ? bf2f(xz[(row0 - 2) * 4096 + c]) : 0.f;
    float x2 = (l0 >= 1) ? bf2f(xz[(row0 - 1) * 4096 + c]) : 0.f;
    long row = row0;
    for (int l = 0; l < LCHUNK; ++l, ++row) {
        float x3 = bf2f(xz[row * 4096 + c]);
        float xc = cbc + x0 * w.x + x1 * w.y + x2 * w.z + x3 * w.w;
        xc = xc / (1.f + __expf(-xc));
        x0 = x1; x1 = x2; x2 = x3;
        float d = bf2f(dlt[row * 2048 + c]);
        const float* __restrict__ bc = dbc + row * 96;
        sumd += d;
        float dx = d * xc;
#pragma unroll
        for (int s = 0; s < 16; ++s)
            h[s] = fexp2(d * A2[s]) * h[s] + dx * bc[64 + s];
    }
    long hb = ((long)(b * NCHUNK + g) * 16) * 2048 + c;
#pragma unroll
    for (int s = 0; s < 16; ++s) hbuf[hb + (long)s * 2048] = h[s];
    sdbuf[(long)(b * NCHUNK + g) * 2048 + c] = sumd;
}

// part2: serial combine over chunks; hbuf becomes h_in per chunk.
__global__ __launch_bounds__(256)
void scan_part2(float* __restrict__ hbuf, const float* __restrict__ sdbuf,
                const float* __restrict__ A_log) {
    int gl = blockIdx.x * 256 + threadIdx.x;   // 131072 threads
    int c = gl & 2047, s = (gl >> 11) & 15, b = gl >> 15;
    float A2 = -__expf(A_log[c * 16 + s]) * LOG2E;
    float hrun = 0.f;
    for (int g = 0; g < NCHUNK; ++g) {
        long hi = ((long)(b * NCHUNK + g) * 16 + s) * 2048 + c;
        float hout = hbuf[hi];
        float sd = sdbuf[(long)(b * NCHUNK + g) * 2048 + c];
        hbuf[hi] = hrun;
        hrun = fexp2(A2 * sd) * hrun + hout;
    }
}

// part3: re-scan from h_in; y = sum_s h*C; D-skip + SiLU gate; y -> dlt (bf16).
__global__ __launch_bounds__(256)
void scan_part3(const ushort* __restrict__ xz,    // xi + z halves (read-only)
                ushort* __restrict__ dlt,         // delta in / gated y out
                const float* __restrict__ dbc,
                const float* __restrict__ A_log,
                const float* __restrict__ cw, const float* __restrict__ cb,
                const float* __restrict__ Dp,
                const float* __restrict__ hbuf) {
    int c = blockIdx.y * 256 + threadIdx.x;
    int b = blockIdx.z, g = blockIdx.x;
    float A2[16], h[16];
#pragma unroll
    for (int s = 0; s < 16; ++s) A2[s] = -__expf(A_log[c * 16 + s]) * LOG2E;
    long hb = ((long)(b * NCHUNK + g) * 16) * 2048 + c;
#pragma unroll
    for (int s = 0; s < 16; ++s) h[s] = hbuf[hb + (long)s * 2048];
    float4 w = ((const float4*)cw)[c];
    float cbc = cb[c];
    float Dc = Dp[c];
    long row0 = (long)b * LSEQ + (long)g * LCHUNK;
    int l0 = g * LCHUNK;
    float x0 = (l0 >= 3) ? bf2f(xz[(row0 - 3) * 4096 + c]) : 0.f;
    float x1 = (l0 >= 2) ? bf2f(xz[(row0 - 2) * 4096 + c]) : 0.f;
    float x2 = (l0 >= 1) ? bf2f(xz[(row0 - 1) * 4096 + c]) : 0.f;
    long row = row0;
    for (int l = 0; l < LCHUNK; ++l, ++row) {
        float x3 = bf2f(xz[row * 4096 + c]);
        float xc = cbc + x0 * w.x + x1 * w.y + x2 * w.z + x3 * w.w;
        xc = xc / (1.f + __expf(-xc));
        x0 = x1; x1 = x2; x2 = x3;
        float d = bf2f(dlt[row * 2048 + c]);
        float z = bf2f(xz[row * 4096 + 2048 + c]);
        const float* __restrict__ bc = dbc + row * 96;
        float dx = d * xc;
        float y = 0.f;
#pragma unroll
        for (int s = 0; s < 16; ++s) {
            h[s] = fexp2(d * A2[s]) * h[s] + dx * bc[64 + s];
            y += h[s] * bc[80 + s];
        }
        float yv = (y + xc * Dc) * (z / (1.f + __expf(-z)));
        dlt[row * 2048 + c] = f2bf(yv);
    }
}

extern "C" void kernel_launch(void* const* d_in, const int* in_sizes, int n_in,
                              void* d_out, int out_size, void* d_ws, size_t ws_size,
                              hipStream_t stream) {
    const float* x        = (const float*)d_in[0];
    const float* rms_w    = (const float*)d_in[1];
    const float* in_proj  = (const float*)d_in[2];
    const float* conv_w   = (const float*)d_in[3];
    const float* conv_b   = (const float*)d_in[4];
    const float* x_proj   = (const float*)d_in[5];
    const float* dt_w     = (const float*)d_in[6];
    const float* dt_b     = (const float*)d_in[7];
    const float* A_log    = (const float*)d_in[8];
    const float* Dp       = (const float*)d_in[9];
    const float* out_proj = (const float*)d_in[10];
    float* out = (float*)d_out;

    char* p = (char*)d_ws;
    ushort* xz  = (ushort*)p;   p += (size_t)ROWS * 4096 * 2;   // 64 MB  xi|z
    ushort* dlt = (ushort*)p;   p += (size_t)ROWS * 2048 * 2;   // 32 MB  delta -> gated y
    float*  dbc = (float*)p;    p += (size_t)ROWS * 96 * 4;     // 3 MB
    ushort* bt1 = (ushort*)p;   p += (size_t)4096 * 1024 * 2;   // 8 MB   in_proj^T
    ushort* bt2 = (ushort*)p;   p += (size_t)1024 * 2048 * 2;   // 4 MB   out_proj^T
    ushort* bt3 = (ushort*)p;   p += (size_t)128 * 2048 * 2;    // 512 KB x_proj^T (96 rows valid)
    ushort* bt4 = (ushort*)p;   p += (size_t)2048 * 64 * 2;     // 256 KB dt_w^T
    ushort* xn  = (ushort*)p;   p += (size_t)ROWS * 1024 * 2;   // 16.78 MB (dead after in_proj)
    float* sdbuf = (float*)p;   p += (size_t)4 * NCHUNK * 2048 * 4; // 1 MB
    float* hbuf  = (float*)xn;  // 4*32*16*2048*4 = 16.78 MB, overlays xn exactly
    // total ~129 MiB

    // 1. prep: weight transposes + RMSNorm -> xn bf16 + dbc zero
    prep_kernel<<<15424, 256, 0, stream>>>(in_proj, bt1, out_proj, bt2,
                                           x_proj, bt3, dt_w, bt4,
                                           x, rms_w, xn, dbc);
    // 2. xz = xn @ in_proj  [8192,1024]@[1024,4096] -> bf16 (DMA MFMA)
    mfma_gemm_dma<0><<<dim3(4096 / 128, ROWS / 128), 256, 0, stream>>>(
        xn, DIM, bt1, 1024, xz, 4096, DIM, nullptr);
    // 3. dbc += silu(conv(xi)) @ x_proj  (fused conv, split-K x4, atomics)
    xproj_conv_gemm<<<dim3(4, ROWS / 128), 256, 0, stream>>>(
        xz, conv_w, conv_b, bt3, dbc);
    // 4. dlt = softplus(dbc[:,:64] @ dt_w + dt_b) -> bf16
    mfma_gemm_dt<<<dim3(2048 / 128, ROWS / 128), 256, 0, stream>>>(
        dbc, 96, bt4, 64, dlt, 2048, DTRANK, dt_b);
    // 5-7. chunked selective scan (conv recomputed via rolling window)
    scan_part1<<<dim3(NCHUNK, DINNER / 256, 4), 256, 0, stream>>>(
        xz, dlt, dbc, A_log, conv_w, conv_b, hbuf, sdbuf);
    scan_part2<<<512, 256, 0, stream>>>(hbuf, sdbuf, A_log);
    scan_part3<<<dim3(NCHUNK, DINNER / 256, 4), 256, 0, stream>>>(
        xz, dlt, dbc, A_log, conv_w, conv_b, Dp, hbuf);
    // 8. out = x + y @ out_proj  [8192,2048]@[2048,1024] -> f32 (DMA MFMA)
    mfma_gemm_dma<2><<<dim3(DIM / 128, ROWS / 128), 256, 0, stream>>>(
        dlt, 2048, bt2, DINNER, out, DIM, DINNER, x);
}